// Round 1
// baseline (2140.711 us; speedup 1.0000x reference)
//
#include <hip/hip_runtime.h>
#include <hip/hip_bf16.h>

// CrossModalDecoderLayer: RMSNorm -> GQA cross-attn -> +gamma_ca*o ; RMSNorm -> top2 MoE -> +gamma_ffn*ffn
// B=4 NT=1024 NI=576 DIM=1536 CDIM=1024 H=12 HK=4 HD=128 E=4 K=2 INTER=6144

#define DIMC 1536
#define CDIMC 1024
#define NTC 1024
#define NIC 576
#define NBATCH 4
#define HC 12
#define HKC 4
#define HDC 128
#define INTERC 6144
#define NEXP 4
#define TTOK 4096
#define EPSF 1e-6f

typedef __attribute__((ext_vector_type(8))) short short8;   // 8 bf16 = 4 VGPR (MFMA A/B frag)
typedef __attribute__((ext_vector_type(4))) float f32x4;    // MFMA C/D frag
typedef __attribute__((ext_vector_type(4))) short s16x4;

__device__ __forceinline__ float bf2f(short s) {
  union { unsigned u; float f; } x; x.u = ((unsigned)(unsigned short)s) << 16; return x.f;
}
__device__ __forceinline__ short f2bf(float f) {
  union { float f; unsigned u; } x; x.f = f;
  unsigned r = x.u + 0x7FFFu + ((x.u >> 16) & 1u);   // RNE
  return (short)(r >> 16);
}
__device__ __forceinline__ int imin(int a, int b) { return a < b ? a : b; }

typedef __attribute__((address_space(1))) const void gvoid_t;
typedef __attribute__((address_space(3))) void lvoid_t;
__device__ __forceinline__ void gload16(const void* g, void* l) {
  __builtin_amdgcn_global_load_lds((gvoid_t*)g, (lvoid_t*)l, 16, 0, 0);
}

// ---------------- transpose + f32/bf16 -> bf16 transposed ----------------
__device__ __forceinline__ float ldf(const float* p) { return *p; }
__device__ __forceinline__ float ldf(const short* p) { return bf2f(*p); }

template <typename T>
__global__ __launch_bounds__(256) void transpose_k(const T* src, short* dst,
    int R, int C, int lds, int ldd, long sB, long sH, long sDz, int nh) {
  __shared__ float tile[32][33];
  int z = blockIdx.z;
  src += (long)(z / nh) * sB + (long)(z % nh) * sH;
  dst += (long)z * sDz;
  int tx = threadIdx.x & 31, ty = threadIdx.x >> 5;
  int c0 = blockIdx.x * 32, r0 = blockIdx.y * 32;
  #pragma unroll
  for (int i = 0; i < 4; i++)
    tile[ty + i*8][tx] = ldf(&src[(long)(r0 + ty + i*8) * lds + c0 + tx]);
  __syncthreads();
  #pragma unroll
  for (int i = 0; i < 4; i++)
    dst[(long)(c0 + ty + i*8) * ldd + r0 + tx] = f2bf(tile[tx][ty + i*8]);
  (void)R; (void)C;
}

// ---------------- plain f32 -> bf16 convert ----------------
__global__ __launch_bounds__(256) void convert_k(const float* src, short* dst, int n) {
  int i = (blockIdx.x * 256 + threadIdx.x) * 4;
  if (i < n) {
    const float4 v = *(const float4*)(src + i);
    s16x4 o; o[0] = f2bf(v.x); o[1] = f2bf(v.y); o[2] = f2bf(v.z); o[3] = f2bf(v.w);
    *(s16x4*)(dst + i) = o;
  }
}

// ---------------- row RMSNorm (DIM=1536), f32 in -> bf16 out ----------------
__global__ __launch_bounds__(256) void rmsnorm_k(const float* in, const float* w, short* outb) {
  int row = blockIdx.x;
  const float* p = in + (long)row * DIMC;
  float ss = 0.f;
  #pragma unroll
  for (int i = 0; i < 6; i++) { float v = p[threadIdx.x + i*256]; ss += v*v; }
  #pragma unroll
  for (int m = 1; m < 64; m <<= 1) ss += __shfl_xor(ss, m);
  __shared__ float red[4];
  int wave = threadIdx.x >> 6, lane = threadIdx.x & 63;
  if (lane == 0) red[wave] = ss;
  __syncthreads();
  ss = red[0] + red[1] + red[2] + red[3];
  float sc = rsqrtf(ss * (1.f / DIMC) + EPSF);
  short* o = outb + (long)row * DIMC;
  #pragma unroll
  for (int i = 0; i < 6; i++) {
    int idx = threadIdx.x + i*256;
    o[idx] = f2bf(p[idx] * sc * w[idx]);
  }
}

// ---------------- per-head RMSNorm (HD=128), bf16 in-place ----------------
__global__ __launch_bounds__(256) void headnorm_k(short* qk, const float* w, int nrows) {
  int row = blockIdx.x * 4 + (threadIdx.x >> 6);
  int lane = threadIdx.x & 63;
  if (row >= nrows) return;
  short* p = qk + (long)row * HDC + lane * 2;
  float v0 = bf2f(p[0]), v1 = bf2f(p[1]);
  float ss = v0*v0 + v1*v1;
  #pragma unroll
  for (int m = 1; m < 64; m <<= 1) ss += __shfl_xor(ss, m);
  float sc = rsqrtf(ss * (1.f / HDC) + EPSF);
  p[0] = f2bf(v0 * sc * w[lane*2]);
  p[1] = f2bf(v1 * sc * w[lane*2 + 1]);
}

// ---------------- softmax over 576 f32, write bf16 in place (ld 1152) ----------------
__global__ __launch_bounds__(256) void softmax_k(float* S) {
  int row = blockIdx.x * 4 + (threadIdx.x >> 6);
  int lane = threadIdx.x & 63;
  float* p = S + (long)row * NIC;
  float v[9];
  float mx = -1e30f;
  #pragma unroll
  for (int i = 0; i < 9; i++) { v[i] = p[lane + i*64]; mx = fmaxf(mx, v[i]); }
  #pragma unroll
  for (int m = 1; m < 64; m <<= 1) mx = fmaxf(mx, __shfl_xor(mx, m));
  float sum = 0.f;
  #pragma unroll
  for (int i = 0; i < 9; i++) { v[i] = __expf(v[i] - mx); sum += v[i]; }
  #pragma unroll
  for (int m = 1; m < 64; m <<= 1) sum += __shfl_xor(sum, m);
  float r = 1.f / sum;
  short* pb = (short*)p;      // bf16 row, ld 1152 elements
  #pragma unroll
  for (int i = 0; i < 9; i++) pb[lane + i*64] = f2bf(v[i] * r);
}

// ---------------- routing: one wave per token ----------------
__global__ __launch_bounds__(256) void route_k(const short* y, const float* wg,
                                               int* cnt, int* list, float* wlist) {
  int t = blockIdx.x * 4 + (threadIdx.x >> 6);
  int lane = threadIdx.x & 63;
  float acc0 = 0, acc1 = 0, acc2 = 0, acc3 = 0;
  const short* yp = y + (long)t * DIMC;
  #pragma unroll
  for (int i = 0; i < 24; i++) {
    int k = lane + i*64;
    float tv = bf2f(yp[k]);
    const float4 g = *(const float4*)(wg + (long)k * 4);
    acc0 += tv * g.x; acc1 += tv * g.y; acc2 += tv * g.z; acc3 += tv * g.w;
  }
  #pragma unroll
  for (int m = 1; m < 64; m <<= 1) {
    acc0 += __shfl_xor(acc0, m); acc1 += __shfl_xor(acc1, m);
    acc2 += __shfl_xor(acc2, m); acc3 += __shfl_xor(acc3, m);
  }
  if (lane == 0) {
    float l[4] = {acc0, acc1, acc2, acc3};
    float mx = fmaxf(fmaxf(l[0], l[1]), fmaxf(l[2], l[3]));
    float p[4];
    #pragma unroll
    for (int e = 0; e < 4; e++) p[e] = __expf(l[e] - mx);
    int e0 = 0;
    #pragma unroll
    for (int e = 1; e < 4; e++) if (p[e] > p[e0]) e0 = e;
    int e1 = -1;
    #pragma unroll
    for (int e = 0; e < 4; e++) if (e != e0 && (e1 < 0 || p[e] > p[e1])) e1 = e;
    float s = p[e0] + p[e1];
    float w0 = p[e0] / s, w1 = p[e1] / s;
    int pos0 = atomicAdd(&cnt[e0], 1);
    list[e0 * TTOK + pos0] = t; wlist[e0 * TTOK + pos0] = w0;
    int pos1 = atomicAdd(&cnt[e1], 1);
    list[e1 * TTOK + pos1] = t; wlist[e1 * TTOK + pos1] = w1;
  }
}

// ---------------- GEMM: C(MxN) = A(MxK,row) * B^T(NxK,row), bf16 MFMA 16x16x32 ----------------
// 128x128 tile, BK=32, 4 waves (2x2), each wave 64x64 = 4x4 frags (m97 structure).
// EPI: 0 bias->bf16 | 1 scale->f32 batched (QK) | 2 plain->bf16 batched (PV)
//      3 oproj: out = hidden + gca*(v+bias) f32 | 4 moe1 dual-B: silu(g)*u->bf16, gathered A rows
//      5 moe2: out[list[row]] += gffn*wlist[row]*v  (scatter accumulate)
struct GArgs {
  const short* A; const short* B0; const short* B1;
  const float* bias; const float* aux0; const float* aux1;
  float* outF; short* outB;
  const int* list; const float* wlist; const int* cntp;
  int M, N, K, lda, ldb, ldc;
  long sAb, sAh, sBb, sBh, sCb, sCh;   // batch strides (z = b*12+h, kh = h/3 for B)
  float scale;
};

template <int EPI, int NBV>
__global__ __launch_bounds__(256, 2) void gemm_k(GArgs a) {
  __shared__ __align__(16) short smem[NBV == 2 ? 12288 : 8192];
  const int tid = threadIdx.x;
  const int lane = tid & 63, wave = tid >> 6;
  const int wr = wave >> 1, wc = wave & 1;
  const int r16 = lane & 15, half = lane >> 4;
  const int m0 = blockIdx.x * 128, n0 = blockIdx.y * 128;
  const int z = blockIdx.z;
  const int bb = z / 12, hh = z - bb * 12, kh = hh / 3;

  int cntv = a.M;
  if (EPI == 4 || EPI == 5) { cntv = *a.cntp; if (m0 >= cntv) return; }

  const short* A = a.A + (long)bb * a.sAb + (long)hh * a.sAh;
  const short* B = a.B0 + (long)bb * a.sBb + (long)kh * a.sBh;

  int ar0 = m0 + (tid >> 2), ar1 = m0 + 64 + (tid >> 2);
  if (EPI == 4) { ar0 = a.list[imin(ar0, cntv - 1)]; ar1 = a.list[imin(ar1, cntv - 1)]; }
  const int br0 = imin(n0 + (tid >> 2), a.N - 1);
  const int br1 = imin(n0 + 64 + (tid >> 2), a.N - 1);
  const int kc = (tid & 3) * 8;

  const short* pA0 = A + (long)ar0 * a.lda + kc;
  const short* pA1 = A + (long)ar1 * a.lda + kc;
  const short* pB0 = B + (long)br0 * a.ldb + kc;
  const short* pB1 = B + (long)br1 * a.ldb + kc;
  const short* pC0 = a.B1 + (long)br0 * a.ldb + kc;
  const short* pC1 = a.B1 + (long)br1 * a.ldb + kc;

  short* ldsA = smem;
  short* ldsB = smem + 4096;
  short* ldsC = smem + 8192;
  const int off = tid * 8;

  f32x4 acc0[4][4], acc1[4][4];
  #pragma unroll
  for (int i = 0; i < 4; i++)
    #pragma unroll
    for (int j = 0; j < 4; j++) { acc0[i][j] = (f32x4){0,0,0,0}; acc1[i][j] = (f32x4){0,0,0,0}; }

  for (int k0 = 0; k0 < a.K; k0 += 32) {
    gload16(pA0, ldsA + off);
    gload16(pA1, ldsA + 2048 + off);
    gload16(pB0, ldsB + off);
    gload16(pB1, ldsB + 2048 + off);
    if (NBV == 2) { gload16(pC0, ldsC + off); gload16(pC1, ldsC + 2048 + off); }
    pA0 += 32; pA1 += 32; pB0 += 32; pB1 += 32; pC0 += 32; pC1 += 32;
    __syncthreads();   // drains vmcnt -> LDS tiles ready
    short8 afr[4], bfr[4], cfr[4];
    #pragma unroll
    for (int m = 0; m < 4; m++) afr[m] = *(const short8*)&ldsA[(wr*64 + m*16 + r16)*32 + half*8];
    #pragma unroll
    for (int n = 0; n < 4; n++) bfr[n] = *(const short8*)&ldsB[(wc*64 + n*16 + r16)*32 + half*8];
    if (NBV == 2) {
      #pragma unroll
      for (int n = 0; n < 4; n++) cfr[n] = *(const short8*)&ldsC[(wc*64 + n*16 + r16)*32 + half*8];
    }
    #pragma unroll
    for (int m = 0; m < 4; m++)
      #pragma unroll
      for (int n = 0; n < 4; n++) {
        acc0[m][n] = __builtin_amdgcn_mfma_f32_16x16x32_bf16(afr[m], bfr[n], acc0[m][n], 0, 0, 0);
        if (NBV == 2)
          acc1[m][n] = __builtin_amdgcn_mfma_f32_16x16x32_bf16(afr[m], cfr[n], acc1[m][n], 0, 0, 0);
      }
    __syncthreads();
  }

  const long cb = (long)bb * a.sCb + (long)hh * a.sCh;
  #pragma unroll
  for (int m = 0; m < 4; m++)
    #pragma unroll
    for (int n = 0; n < 4; n++)
      #pragma unroll
      for (int j = 0; j < 4; j++) {
        const int row = m0 + wr*64 + m*16 + half*4 + j;   // C/D: row=(lane>>4)*4+reg
        const int col = n0 + wc*64 + n*16 + r16;          //      col=lane&15
        float v = acc0[m][n][j];
        if (EPI == 0) {
          v += a.bias[col];
          a.outB[(long)row * a.ldc + col] = f2bf(v);
        } else if (EPI == 1) {
          if (col < a.N) a.outF[cb + (long)row * a.ldc + col] = v * a.scale;
        } else if (EPI == 2) {
          a.outB[cb + (long)row * a.ldc + col] = f2bf(v);
        } else if (EPI == 3) {
          v += a.bias[col];
          const long idx = (long)row * a.ldc + col;
          a.outF[idx] = a.aux0[idx] + a.aux1[col] * v;
        } else if (EPI == 4) {
          const float g = v, u = acc1[m][n][j];
          const float sg = 1.f / (1.f + __expf(-g));
          a.outB[(long)row * a.ldc + col] = f2bf(g * sg * u);
        } else {
          if (row < cntv) {
            const int t = a.list[row];
            a.outF[(long)t * a.ldc + col] += a.aux1[col] * a.wlist[row] * v;
          }
        }
      }
}

// ---------------- host ----------------
extern "C" void kernel_launch(void* const* d_in, const int* in_sizes, int n_in,
                              void* d_out, int out_size, void* d_ws, size_t ws_size,
                              hipStream_t stream) {
  const float* hidden = (const float*)d_in[0];
  const float* context = (const float*)d_in[1];
  // d_in[2] context_mask: all-true, ignored
  const float* w_ln1 = (const float*)d_in[3];
  const float* w_ln2 = (const float*)d_in[4];
  const float* wq = (const float*)d_in[5];
  const float* bq = (const float*)d_in[6];
  const float* wk = (const float*)d_in[7];
  const float* bk = (const float*)d_in[8];
  const float* wv = (const float*)d_in[9];
  const float* bv = (const float*)d_in[10];
  const float* wo = (const float*)d_in[11];
  const float* bo = (const float*)d_in[12];
  const float* wqn = (const float*)d_in[13];
  const float* wkn = (const float*)d_in[14];
  const float* gca = (const float*)d_in[15];
  const float* gffn = (const float*)d_in[16];
  const float* wgate = (const float*)d_in[17];
  const float* wg = (const float*)d_in[18];
  const float* wu = (const float*)d_in[19];
  const float* wd = (const float*)d_in[20];
  float* out = (float*)d_out;
  (void)in_sizes; (void)n_in; (void)out_size; (void)ws_size;

  char* base = (char*)d_ws;
  size_t off = 0;
  auto alloc = [&](size_t bytes) -> char* {
    char* p = base + off;
    off += (bytes + 255) & ~(size_t)255;
    return p;
  };
  short* wq_t = (short*)alloc((size_t)DIMC * DIMC * 2);
  short* wk_t = (short*)alloc((size_t)CDIMC * 512 * 2);
  short* wv_t = (short*)alloc((size_t)CDIMC * 512 * 2);
  short* wo_t = (short*)alloc((size_t)DIMC * DIMC * 2);
  short* ctxb = (short*)alloc((size_t)NBATCH * NIC * CDIMC * 2);
  short* xln  = (short*)alloc((size_t)TTOK * DIMC * 2);        // later reused as ybuf
  short* qbuf = (short*)alloc((size_t)TTOK * DIMC * 2);        // later reused as obuf
  short* kbuf = (short*)alloc((size_t)NBATCH * NIC * 512 * 2);
  short* vbuf = (short*)alloc((size_t)NBATCH * NIC * 512 * 2);
  short* v_t  = (short*)alloc((size_t)NBATCH * HKC * HDC * NIC * 2);
  float* Sbuf = (float*)alloc((size_t)NBATCH * HC * NTC * NIC * 4); // later reused as act (bf16 4096x6144)
  short* wgt  = (short*)alloc((size_t)INTERC * DIMC * 2);
  short* wut  = (short*)alloc((size_t)INTERC * DIMC * 2);
  short* wdt  = (short*)alloc((size_t)DIMC * INTERC * 2);
  int*   cnt  = (int*)alloc(256);
  int*   list = (int*)alloc((size_t)NEXP * TTOK * 4);
  float* wls  = (float*)alloc((size_t)NEXP * TTOK * 4);
  short* ybuf = xln;
  short* obuf = qbuf;
  short* act  = (short*)Sbuf;

  dim3 blk(256);
  hipMemsetAsync(cnt, 0, 16, stream);

  // weight transposes f32 -> bf16 (B^T layout for GEMM)
  transpose_k<float><<<dim3(48,48,1), blk, 0, stream>>>(wq, wq_t, 1536,1536, 1536,1536, 0,0,0, 1);
  transpose_k<float><<<dim3(16,32,1), blk, 0, stream>>>(wk, wk_t, 1024,512, 512,1024, 0,0,0, 1);
  transpose_k<float><<<dim3(16,32,1), blk, 0, stream>>>(wv, wv_t, 1024,512, 512,1024, 0,0,0, 1);
  transpose_k<float><<<dim3(48,48,1), blk, 0, stream>>>(wo, wo_t, 1536,1536, 1536,1536, 0,0,0, 1);
  convert_k<<<dim3(2304), blk, 0, stream>>>(context, ctxb, NBATCH * NIC * CDIMC);
  rmsnorm_k<<<dim3(4096), blk, 0, stream>>>(hidden, w_ln1, xln);

  { GArgs a{}; a.A=xln; a.B0=wq_t; a.B1=wq_t; a.bias=bq; a.outB=qbuf;
    a.M=4096; a.N=1536; a.K=1536; a.lda=1536; a.ldb=1536; a.ldc=1536;
    gemm_k<0,1><<<dim3(32,12,1), blk, 0, stream>>>(a); }
  { GArgs a{}; a.A=ctxb; a.B0=wk_t; a.B1=wk_t; a.bias=bk; a.outB=kbuf;
    a.M=2304; a.N=512; a.K=1024; a.lda=1024; a.ldb=1024; a.ldc=512;
    gemm_k<0,1><<<dim3(18,4,1), blk, 0, stream>>>(a); }
  { GArgs a{}; a.A=ctxb; a.B0=wv_t; a.B1=wv_t; a.bias=bv; a.outB=vbuf;
    a.M=2304; a.N=512; a.K=1024; a.lda=1024; a.ldb=1024; a.ldc=512;
    gemm_k<0,1><<<dim3(18,4,1), blk, 0, stream>>>(a); }

  headnorm_k<<<dim3(12288), blk, 0, stream>>>(qbuf, wqn, 49152);
  headnorm_k<<<dim3(2304), blk, 0, stream>>>(kbuf, wkn, 9216);
  // V^T per (b,kh): 576x128 -> 128x576
  transpose_k<short><<<dim3(4,18,16), blk, 0, stream>>>(vbuf, v_t, 576,128, 512,576,
                                                        (long)576*512, 128L, (long)128*576, 4);
  // S = scale * Q K^T   (batched over z=b*12+h)
  { GArgs a{}; a.A=qbuf; a.B0=kbuf; a.B1=kbuf; a.outF=Sbuf;
    a.M=1024; a.N=576; a.K=128; a.lda=1536; a.ldb=512; a.ldc=576;
    a.sAb=(long)1024*1536; a.sAh=128; a.sBb=(long)576*512; a.sBh=128;
    a.sCb=(long)12*1024*576; a.sCh=(long)1024*576; a.scale=0.08838834764831845f;
    gemm_k<1,1><<<dim3(8,5,48), blk, 0, stream>>>(a); }
  softmax_k<<<dim3(12288), blk, 0, stream>>>(Sbuf);
  // O = P V  (P bf16 in-place in Sbuf, ld 1152)
  { GArgs a{}; a.A=(const short*)Sbuf; a.B0=v_t; a.B1=v_t; a.outB=obuf;
    a.M=1024; a.N=128; a.K=576; a.lda=1152; a.ldb=576; a.ldc=1536;
    a.sAb=(long)12*1024*1152; a.sAh=(long)1024*1152; a.sBb=(long)4*128*576; a.sBh=(long)128*576;
    a.sCb=(long)1024*1536; a.sCh=128;
    gemm_k<2,1><<<dim3(8,1,48), blk, 0, stream>>>(a); }
  // h = hidden + gca*(O Wo + bo) -> d_out (f32)
  { GArgs a{}; a.A=obuf; a.B0=wo_t; a.B1=wo_t; a.bias=bo; a.aux0=hidden; a.aux1=gca; a.outF=out;
    a.M=4096; a.N=1536; a.K=1536; a.lda=1536; a.ldb=1536; a.ldc=1536;
    gemm_k<3,1><<<dim3(32,12,1), blk, 0, stream>>>(a); }

  rmsnorm_k<<<dim3(4096), blk, 0, stream>>>(out, w_ln2, ybuf);
  route_k<<<dim3(1024), blk, 0, stream>>>(ybuf, wgate, cnt, list, wls);

  for (int e = 0; e < NEXP; e++) {
    transpose_k<float><<<dim3(192,48,1), blk, 0, stream>>>(wg + (long)e*DIMC*INTERC, wgt,
                                                           1536,6144, 6144,1536, 0,0,0, 1);
    transpose_k<float><<<dim3(192,48,1), blk, 0, stream>>>(wu + (long)e*DIMC*INTERC, wut,
                                                           1536,6144, 6144,1536, 0,0,0, 1);
    transpose_k<float><<<dim3(48,192,1), blk, 0, stream>>>(wd + (long)e*INTERC*DIMC, wdt,
                                                           6144,1536, 1536,6144, 0,0,0, 1);
    { GArgs a{}; a.A=ybuf; a.B0=wgt; a.B1=wut; a.outB=act;
      a.M=4096; a.N=6144; a.K=1536; a.lda=1536; a.ldb=1536; a.ldc=6144;
      a.list=list + e*TTOK; a.cntp=cnt + e;
      gemm_k<4,2><<<dim3(32,48,1), blk, 0, stream>>>(a); }
    { GArgs a{}; a.A=act; a.B0=wdt; a.B1=wdt; a.outF=out; a.aux1=gffn;
      a.M=4096; a.N=1536; a.K=6144; a.lda=6144; a.ldb=6144; a.ldc=1536;
      a.list=list + e*TTOK; a.wlist=wls + e*TTOK; a.cntp=cnt + e;
      gemm_k<5,1><<<dim3(32,12,1), blk, 0, stream>>>(a); }
  }
}